// Round 1
// 343.187 us; speedup vs baseline: 1.1267x; 1.1267x over previous
//
#include <hip/hip_runtime.h>
#include <math.h>

#define T_SEQ 2048
#define C_DIM 2048
#define NH    16
#define NG    4
#define DH    128
#define BATCH 2

typedef unsigned short u16;
typedef __bf16 bf16_t;
typedef bf16_t bf16x8 __attribute__((ext_vector_type(8)));
typedef float  f32x4  __attribute__((ext_vector_type(4)));

static __device__ __forceinline__ u16 f2bf(float f) {
    return __builtin_bit_cast(u16, (__bf16)f);
}

// async global->LDS, 16B per lane. lds must be wave-uniform base; HW adds lane*16.
static __device__ __forceinline__ void gll16(const void* g, void* lds) {
    __builtin_amdgcn_global_load_lds(
        (const __attribute__((address_space(1))) void*)(unsigned long long)(g),
        (__attribute__((address_space(3))) void*)(unsigned int)(unsigned long long)(lds),
        16, 0, 0);
}

// ---------------------------------------------------------------------------
// fused fp32->bf16 cast for x, Wq, Wk, Wv (8 elems/thread, flat if-chain)
// chunk counts: x 1048576 | Wq 524288 | Wk 131072 | Wv 131072  (sum = 7168*256)
// ---------------------------------------------------------------------------
__global__ __launch_bounds__(256)
void cast_multi(const float* __restrict__ x,  const float* __restrict__ wq,
                const float* __restrict__ wk, const float* __restrict__ wv,
                u16* __restrict__ xo, u16* __restrict__ wqo,
                u16* __restrict__ wko, u16* __restrict__ wvo) {
    int i = blockIdx.x * 256 + threadIdx.x;
    const float* src; u16* dst; int off;
    if (i < 1048576)      { src = x;  dst = xo;  off = i; }
    else if (i < 1572864) { src = wq; dst = wqo; off = i - 1048576; }
    else if (i < 1703936) { src = wk; dst = wko; off = i - 1572864; }
    else                  { src = wv; dst = wvo; off = i - 1703936; }
    const float4* p = (const float4*)src + (size_t)off * 2;
    float4 a = p[0], b = p[1];
    u16 u[8] = {f2bf(a.x), f2bf(a.y), f2bf(a.z), f2bf(a.w),
                f2bf(b.x), f2bf(b.y), f2bf(b.z), f2bf(b.w)};
    *(uint4*)(dst + (size_t)off * 8) = *(const uint4*)u;
}

__global__ __launch_bounds__(256)
void cast_f32_bf16(const float* __restrict__ in, u16* __restrict__ out, int n8) {
    int i = blockIdx.x * 256 + threadIdx.x;
    if (i >= n8) return;
    const float4* p = (const float4*)in + (size_t)i * 2;
    float4 a = p[0], b = p[1];
    u16 u[8] = {f2bf(a.x), f2bf(a.y), f2bf(a.z), f2bf(a.w),
                f2bf(b.x), f2bf(b.y), f2bf(b.z), f2bf(b.w)};
    *(uint4*)(out + (size_t)i * 8) = *(const uint4*)u;
}

// ---------------------------------------------------------------------------
// C(fp32, M x N) = A_bf16(M,K) @ B_bf16(N,K)^T (+bias)
// 128x128 tile, BK=32, 4 waves, each wave 64x64 (4x4 MFMA 16x16x32).
// ---------------------------------------------------------------------------
static __device__ __forceinline__ void gemm_body(
        u16* As, u16* Bs,
        const u16* __restrict__ A, const u16* __restrict__ B,
        const float* __restrict__ bias, float* __restrict__ C,
        int N, int K, int m0, int n0) {
    const int t    = threadIdx.x;
    const int lane = t & 63, w = t >> 6;
    const int l15  = lane & 15, quad = lane >> 4;
    const int wr   = w >> 1, wc = w & 1;

    f32x4 acc[4][4];
#pragma unroll
    for (int mt = 0; mt < 4; ++mt)
#pragma unroll
        for (int nt = 0; nt < 4; ++nt) acc[mt][nt] = (f32x4){0.f, 0.f, 0.f, 0.f};

    const int off0 = w*2048 + lane*16;
    const int r0 = off0 >> 6,          c0 = (off0 & 63) >> 1;
    const int r1 = (off0+1024) >> 6,   c1 = ((off0+1024) & 63) >> 1;
    const u16* Ag0 = A + (size_t)(m0 + r0) * K + c0;
    const u16* Ag1 = A + (size_t)(m0 + r1) * K + c1;
    const u16* Bg0 = B + (size_t)(n0 + r0) * K + c0;
    const u16* Bg1 = B + (size_t)(n0 + r1) * K + c1;
    char* AsB = (char*)As; char* BsB = (char*)Bs;
    const int ldsOff0 = w*2048, ldsOff1 = w*2048 + 1024;

    for (int k0 = 0; k0 < K; k0 += 32) {
        gll16(Ag0 + k0, AsB + ldsOff0);
        gll16(Ag1 + k0, AsB + ldsOff1);
        gll16(Bg0 + k0, BsB + ldsOff0);
        gll16(Bg1 + k0, BsB + ldsOff1);
        __syncthreads();
        bf16x8 af[4], bf[4];
#pragma unroll
        for (int mt = 0; mt < 4; ++mt)
            af[mt] = __builtin_bit_cast(bf16x8,
                *(const uint4*)&As[(wr*64 + mt*16 + l15)*32 + quad*8]);
#pragma unroll
        for (int nt = 0; nt < 4; ++nt)
            bf[nt] = __builtin_bit_cast(bf16x8,
                *(const uint4*)&Bs[(wc*64 + nt*16 + l15)*32 + quad*8]);
#pragma unroll
        for (int mt = 0; mt < 4; ++mt)
#pragma unroll
            for (int nt = 0; nt < 4; ++nt)
                acc[mt][nt] = __builtin_amdgcn_mfma_f32_16x16x32_bf16(
                                  af[mt], bf[nt], acc[mt][nt], 0, 0, 0);
        __syncthreads();
    }

#pragma unroll
    for (int mt = 0; mt < 4; ++mt)
#pragma unroll
        for (int nt = 0; nt < 4; ++nt) {
            const int col = n0 + wc*64 + nt*16 + l15;
            const float bv = bias ? bias[col] : 0.f;
#pragma unroll
            for (int r = 0; r < 4; ++r) {
                const int row = m0 + wr*64 + mt*16 + quad*4 + r;
                C[(size_t)row * N + col] = acc[mt][nt][r] + bv;
            }
        }
}

__global__ __launch_bounds__(256)
void gemm_nt_bf16(const u16* __restrict__ A, const u16* __restrict__ B,
                  const float* __restrict__ bias, float* __restrict__ C,
                  int N, int K) {
    __shared__ __align__(16) u16 As[128*32];
    __shared__ __align__(16) u16 Bs[128*32];
    gemm_body(As, Bs, A, B, bias, C, N, K, blockIdx.y*128, blockIdx.x*128);
}

// fused Q/K/V projections: blockIdx.x 0..15 -> Q cols, 16..19 -> K, 20..23 -> V
__global__ __launch_bounds__(256)
void gemm_qkv(const u16* __restrict__ A,  const u16* __restrict__ Bq,
              const u16* __restrict__ Bk, const u16* __restrict__ Bv,
              float* __restrict__ Cq, float* __restrict__ Ck, float* __restrict__ Cv) {
    __shared__ __align__(16) u16 As[128*32];
    __shared__ __align__(16) u16 Bs[128*32];
    const int bx = blockIdx.x;
    const u16* B; float* C; int N, n0;
    if (bx < 16)      { B = Bq; C = Cq; N = 2048; n0 = bx * 128; }
    else if (bx < 20) { B = Bk; C = Ck; N = 512;  n0 = (bx-16) * 128; }
    else              { B = Bv; C = Cv; N = 512;  n0 = (bx-20) * 128; }
    gemm_body(As, Bs, A, B, nullptr, C, N, 2048, blockIdx.y*128, n0);
}

// ---------------------------------------------------------------------------
// Fused RMSNorm + RoPE for q and k, fp32 in -> bf16 out.
// blocks [0, 16384): q rows; [16384, 20480): k rows. One wave per D=128 row.
// ---------------------------------------------------------------------------
__global__ __launch_bounds__(256)
void rmsnorm_rope_qk(const float* __restrict__ qf, const float* __restrict__ kf,
                     const float* __restrict__ qw, const float* __restrict__ kw,
                     u16* __restrict__ qo, u16* __restrict__ ko) {
    const int blk  = blockIdx.x;
    const int sub  = threadIdx.x >> 6;
    const int lane = threadIdx.x & 63;
    const float* in; const float* w; u16* out; int row, nheads; float scale;
    if (blk < 16384) {
        in = qf; w = qw; out = qo; nheads = NH; scale = 0.08838834764831845f;
        row = blk * 4 + sub;
    } else {
        in = kf; w = kw; out = ko; nheads = NG; scale = 1.0f;
        row = (blk - 16384) * 4 + sub;
    }
    const float* p = in + (size_t)row * 128;
    float x1 = p[lane], x2 = p[lane + 64];
    float ss = x1*x1 + x2*x2;
#pragma unroll
    for (int off = 32; off >= 1; off >>= 1) ss += __shfl_xor(ss, off, 64);
    float inv = 1.0f / (sqrtf(ss * (1.0f/128.0f)) + 1e-6f);
    float x1n = w[lane]      * x1 * inv;
    float x2n = w[lane + 64] * x2 * inv;
    int tpos = (row / nheads) & (T_SEQ - 1);
    float invfreq = powf(10000.0f, -(float)lane / 64.0f);
    float s, c;
    sincosf((float)tpos * invfreq, &s, &c);
    out[(size_t)row*128 + lane]      = f2bf((x1n * c + x2n * s) * scale);
    out[(size_t)row*128 + lane + 64] = f2bf((x2n * c - x1n * s) * scale);
}

// ---------------------------------------------------------------------------
// V cast fp32->bf16 + transpose: v (B,T,G,D) -> vt (B,G,D,T).
// ---------------------------------------------------------------------------
__global__ __launch_bounds__(256)
void v_cast_transpose(const float* __restrict__ v, u16* __restrict__ vt) {
    __shared__ u16 Lt[128 * 66];
    const int t  = threadIdx.x;
    const int t0 = blockIdx.x * 64;
    const int bg = blockIdx.y;
    const int b  = bg / NG, g = bg % NG;
#pragma unroll
    for (int rep = 0; rep < 8; ++rep) {
        int idx = rep * 256 + t;
        int i   = idx >> 5;
        int c   = idx & 31;
        float4 f = *(const float4*)(v + ((size_t)(b*T_SEQ + t0 + i)*NG + g)*DH + c*4);
        Lt[(c*4+0)*66 + i] = f2bf(f.x);
        Lt[(c*4+1)*66 + i] = f2bf(f.y);
        Lt[(c*4+2)*66 + i] = f2bf(f.z);
        Lt[(c*4+3)*66 + i] = f2bf(f.w);
    }
    __syncthreads();
#pragma unroll
    for (int rep = 0; rep < 4; ++rep) {
        int idx = rep * 256 + t;
        int d = idx >> 3, c = idx & 7;
        const u16* src = &Lt[d*66 + c*8];
        uint4 val;
        val.x = *(const unsigned int*)(src + 0);
        val.y = *(const unsigned int*)(src + 2);
        val.z = *(const unsigned int*)(src + 4);
        val.w = *(const unsigned int*)(src + 6);
        *(uint4*)(vt + ((size_t)(bg*DH + d))*T_SEQ + t0 + c*8) = val;
    }
}

// ---------------------------------------------------------------------------
// MFMA flash attention v6.
// Block = 256 thr = 4 waves = 4 heads (one GQA group) x 32 queries.
// Each wave owns 32 q-rows (2x16 row-groups): every K/V LDS fragment read
// feeds TWO MFMAs -> halves LDS read traffic vs v4 (was LDS-BW-bound:
// MfmaUtil 11%, HBM 6%, 9.2M bank-conflict cycles).
// K/V staged via global_load_lds DMA with PRE-SWIZZLED global source
// (linear LDS dest + XOR-swizzled content, rule #21), double-buffered ->
// ONE barrier per tile. All LDS tiles XOR-swizzled (elem ^= (row&7)<<3):
// b128 reads bank-uniform, P b16 stores 2-way (free).
// LDS 72KB -> 2 blocks/CU. Chunk pairing (b=0 reversed) balances CU load.
// ---------------------------------------------------------------------------
__global__ __launch_bounds__(256, 2)
void flash_attn_mfma(const u16* __restrict__ qh, const u16* __restrict__ kh,
                     const u16* __restrict__ vt, u16* __restrict__ y) {
    __shared__ __align__(16) u16 Ks[2][64*128];   // [buf][key][d]   swizzled
    __shared__ __align__(16) u16 Vs[2][128*64];   // [buf][d][key]   swizzled
    __shared__ __align__(16) u16 Ps[64*64];       // [4 waves x 16 rows][key]

    const int t    = threadIdx.x;
    const int lane = t & 63, w = t >> 6;            // w = 0..3 = head-in-group
    const int l15  = lane & 15, quad = lane >> 4;
    const int bg   = blockIdx.y;
    const int b    = bg >> 2, g = bg & 3;
    const int chunk = b ? (int)blockIdx.x : (63 - (int)blockIdx.x);
    const int q0   = chunk * 32;
    const int h    = g * (NH / NG) + w;

    const float L2E = 1.4426950408889634f;

    // Q fragments for both 16-row groups (A-operand: row=l15, k=quad*8..)
    bf16x8 aq[2][4];
#pragma unroll
    for (int m = 0; m < 2; ++m) {
        const u16* qp = qh + ((size_t)(b*T_SEQ + q0 + m*16 + l15) * NH + h) * DH;
#pragma unroll
        for (int kc = 0; kc < 4; ++kc)
            aq[m][kc] = __builtin_bit_cast(bf16x8, *(const uint4*)(qp + kc*32 + quad*8));
    }

    f32x4 accO[2][8];
#pragma unroll
    for (int m = 0; m < 2; ++m)
#pragma unroll
        for (int nd = 0; nd < 8; ++nd) accO[m][nd] = (f32x4){0.f, 0.f, 0.f, 0.f};
    float ls[2][4] = {{0.f,0.f,0.f,0.f},{0.f,0.f,0.f,0.f}};

    const u16* kgb = kh + ((size_t)b*T_SEQ*NG + g)*DH;
    const u16* vgb = vt + ((size_t)(b*NG + g)*DH)*T_SEQ;

    // DMA staging roles (per thread, 4 passes each for K and V):
    // dest is LINEAR (wave-uniform base + lane*16); source carries the swizzle.
    const int krb = t >> 4, kcl = t & 15;
    const int vdb = t >> 3, vcl = t & 7;

    const int ktiles = q0/64 + 1;

    // prologue: stage tile 0 -> buf 0
#pragma unroll
    for (int j = 0; j < 4; ++j) {
        const int kr = j*16 + krb;
        gll16(kgb + (size_t)kr*(NG*DH) + ((kcl ^ (kr & 7)) << 3),
              (char*)Ks[0] + j*4096 + w*1024);
        const int vd = j*32 + vdb;
        gll16(vgb + (size_t)vd*T_SEQ + ((vcl ^ (vd & 7)) << 3),
              (char*)Vs[0] + j*4096 + w*1024);
    }

    for (int kt = 0; kt < ktiles; ++kt) {
        // syncthreads drains vmcnt(0): buf[kt&1] staged by ALL waves & visible;
        // also fences buf[(kt+1)&1] reads (iter kt-1) from the stage below.
        asm volatile("s_waitcnt vmcnt(0)" ::: "memory");
        __syncthreads();

        if (kt + 1 < ktiles) {          // issue next-tile DMA, overlaps compute
            const int k0n = (kt + 1) * 64, bn = (kt + 1) & 1;
#pragma unroll
            for (int j = 0; j < 4; ++j) {
                const int kr = j*16 + krb;
                gll16(kgb + (size_t)(k0n + kr)*(NG*DH) + ((kcl ^ (kr & 7)) << 3),
                      (char*)Ks[bn] + j*4096 + w*1024);
                const int vd = j*32 + vdb;
                gll16(vgb + (size_t)vd*T_SEQ + k0n + ((vcl ^ (vd & 7)) << 3),
                      (char*)Vs[bn] + j*4096 + w*1024);
            }
        }

        const u16* Kb = Ks[kt & 1];
        const u16* Vb = Vs[kt & 1];
        const int k0 = kt * 64;

        // --- S = Q K^T : 32 rows x 64 keys, K-fragments shared by both groups
        f32x4 accS[2][4];
#pragma unroll
        for (int m = 0; m < 2; ++m)
#pragma unroll
            for (int nt = 0; nt < 4; ++nt) accS[m][nt] = (f32x4){0.f,0.f,0.f,0.f};

#pragma unroll
        for (int nt = 0; nt < 4; ++nt) {
            const int krow = nt*16 + l15;
            const int kswz = (krow & 7) << 3;
#pragma unroll
            for (int kc = 0; kc < 4; ++kc) {
                bf16x8 bk = __builtin_bit_cast(bf16x8,
                    *(const uint4*)&Kb[krow*128 + ((kc*32 + quad*8) ^ kswz)]);
                accS[0][nt] = __builtin_amdgcn_mfma_f32_16x16x32_bf16(aq[0][kc], bk, accS[0][nt], 0, 0, 0);
                accS[1][nt] = __builtin_amdgcn_mfma_f32_16x16x32_bf16(aq[1][kc], bk, accS[1][nt], 0, 0, 0);
            }
        }

        // --- soft-cap + causal + exp2 per row-group; P via swizzled LDS ---
        bf16x8 ap[2][2];
#pragma unroll
        for (int m = 0; m < 2; ++m) {
#pragma unroll
            for (int nt = 0; nt < 4; ++nt) {
                const int colg = k0 + nt*16 + l15;
#pragma unroll
                for (int r = 0; r < 4; ++r) {
                    const int rowg = q0 + m*16 + quad*4 + r;
                    float s = accS[m][nt][r];
                    float z = s * 0.02f;          // s/50
                    float u = z * z;
                    float poly = fmaf(u, fmaf(u, fmaf(u, -0.05396825396825397f,
                                           0.13333333333333333f),
                                          -0.3333333333333333f), 1.0f);
                    float p = __builtin_amdgcn_exp2f(s * poly * L2E);
                    p = (colg > rowg) ? 0.f : p;
                    ls[m][r] += p;
                    const int prow = w*16 + quad*4 + r;
                    Ps[prow*64 + ((nt*16 + l15) ^ ((prow & 7) << 3))] = f2bf(p);
                }
            }
            const int arow = w*16 + l15;
            const int aswz = (arow & 7) << 3;
            ap[m][0] = __builtin_bit_cast(bf16x8,
                *(const uint4*)&Ps[arow*64 + ((quad*8)      ^ aswz)]);
            ap[m][1] = __builtin_bit_cast(bf16x8,
                *(const uint4*)&Ps[arow*64 + ((32 + quad*8) ^ aswz)]);
        }

        // --- O += P V : V-fragments shared by both row-groups ---
#pragma unroll
        for (int nd = 0; nd < 8; ++nd) {
            const int vrow = nd*16 + l15;
            const int vswz = (vrow & 7) << 3;
#pragma unroll
            for (int kc = 0; kc < 2; ++kc) {
                bf16x8 bv = __builtin_bit_cast(bf16x8,
                    *(const uint4*)&Vb[vrow*64 + ((kc*32 + quad*8) ^ vswz)]);
                accO[0][nd] = __builtin_amdgcn_mfma_f32_16x16x32_bf16(ap[0][kc], bv, accO[0][nd], 0, 0, 0);
                accO[1][nd] = __builtin_amdgcn_mfma_f32_16x16x32_bf16(ap[1][kc], bv, accO[1][nd], 0, 0, 0);
            }
        }
    }

    // --- final row-sum reduction across the 16 l15 lanes, write y ---
#pragma unroll
    for (int m = 0; m < 2; ++m)
#pragma unroll
        for (int r = 0; r < 4; ++r) {
            float v = ls[m][r];
            v += __shfl_xor(v, 1, 64);
            v += __shfl_xor(v, 2, 64);
            v += __shfl_xor(v, 4, 64);
            v += __shfl_xor(v, 8, 64);
            const float invl = 1.f / v;
            u16* yp = y + (size_t)(b*T_SEQ + q0 + m*16 + quad*4 + r) * C_DIM + h*DH;
#pragma unroll
            for (int nd = 0; nd < 8; ++nd)
                yp[nd*16 + l15] = f2bf(accO[m][nd][r] * invl);
        }
}

// ---------------------------------------------------------------------------
extern "C" void kernel_launch(void* const* d_in, const int* in_sizes, int n_in,
                              void* d_out, int out_size, void* d_ws, size_t ws_size,
                              hipStream_t stream) {
    const float* x  = (const float*)d_in[0];
    const float* Wq = (const float*)d_in[1];
    const float* Wk = (const float*)d_in[2];
    const float* Wv = (const float*)d_in[3];
    const float* Wo = (const float*)d_in[4];
    const float* bo = (const float*)d_in[5];
    const float* qw = (const float*)d_in[6];
    const float* kw = (const float*)d_in[7];
    float* out = (float*)d_out;

    const size_t qE = (size_t)BATCH * T_SEQ * NH * DH;   // 8,388,608
    const size_t kE = (size_t)BATCH * T_SEQ * NG * DH;   // 2,097,152
    const size_t wqE = (size_t)C_DIM * C_DIM;            // 4,194,304

    float* qf  = (float*)d_ws;          // qE floats
    float* kf  = qf + qE;               // kE floats
    float* vf  = kf + kE;               // kE floats
    u16*   qh  = (u16*)(vf + kE);       // qE
    u16*   khb = qh + qE;               // kE
    u16*   vtb = khb + kE;              // kE
    u16*   xh  = vtb + kE;              // qE
    u16*   wqh = xh + qE;               // wqE
    u16*   wkh = wqh + wqE;             // wkE
    u16*   wvh = wkh + (size_t)(NG*DH)*C_DIM;            // wkE
    u16*   woh = (u16*)kf;              // wqE (reuses kf: dead after rmsnorm)
    u16*   yh  = (u16*)qf;              // qE  (reuses qf: dead after rmsnorm)

    const int M = BATCH * T_SEQ;   // 4096
    dim3 blk(256);

    cast_multi<<<dim3(7168), blk, 0, stream>>>(x, Wq, Wk, Wv, xh, wqh, wkh, wvh);

    gemm_qkv<<<dim3(24, M/128), blk, 0, stream>>>(xh, wqh, wkh, wvh, qf, kf, vf);

    rmsnorm_rope_qk<<<dim3(M*NH/4 + M*NG/4), blk, 0, stream>>>(qf, kf, qw, kw, qh, khb);
    v_cast_transpose<<<dim3(T_SEQ/64, BATCH*NG), blk, 0, stream>>>(vf, vtb);

    cast_f32_bf16<<<dim3(wqE/8/256), blk, 0, stream>>>(Wo, woh, wqE/8);

    flash_attn_mfma<<<dim3(T_SEQ/32, BATCH*NG), dim3(256), 0, stream>>>(qh, khb, vtb, yh);

    gemm_nt_bf16<<<dim3(C_DIM/128, M/128), blk, 0, stream>>>(yh, woh, bo, out, C_DIM, C_DIM);
}